// Round 1
// baseline (142.821 us; speedup 1.0000x reference)
//
#include <hip/hip_runtime.h>
#include <hip/hip_bf16.h>
#include <math.h>

#define D      256
#define N2     8192
#define NHALF  4096

typedef __bf16 bf16x8_t __attribute__((ext_vector_type(8)));
typedef __bf16 bf16x4_t __attribute__((ext_vector_type(4)));
typedef float  f32x4_t  __attribute__((ext_vector_type(4)));

// ---------------- kernel 1: fused normalize + positives + denom-zero ----------------
__global__ __launch_bounds__(256) void prep_kernel(const float* __restrict__ a,
                                                   const float* __restrict__ b,
                                                   __bf16* __restrict__ zb,
                                                   float* __restrict__ g_pos,
                                                   float* __restrict__ g_denom) {
    const int tid = threadIdx.x;
    const int gt  = blockIdx.x * 256 + tid;
    if (gt < N2) g_denom[gt] = 0.0f;

    const int w = blockIdx.x * 4 + (tid >> 6);  // pair row in [0, NHALF)
    const int l = tid & 63;
    float4 x = ((const float4*)(a + (size_t)w * D))[l];
    float4 y = ((const float4*)(b + (size_t)w * D))[l];
    float sxx = x.x * x.x + x.y * x.y + x.z * x.z + x.w * x.w;
    float syy = y.x * y.x + y.y * y.y + y.z * y.z + y.w * y.w;
    float sxy = x.x * y.x + x.y * y.y + x.z * y.z + x.w * y.w;
    #pragma unroll
    for (int off = 32; off; off >>= 1) {
        sxx += __shfl_xor(sxx, off, 64);
        syy += __shfl_xor(syy, off, 64);
        sxy += __shfl_xor(sxy, off, 64);
    }
    const float rx = 1.0f / fmaxf(sqrtf(sxx), 1e-8f);
    const float ry = 1.0f / fmaxf(sqrtf(syy), 1e-8f);

    bf16x4_t ox, oy;
    ox[0] = (__bf16)(x.x * rx); ox[1] = (__bf16)(x.y * rx);
    ox[2] = (__bf16)(x.z * rx); ox[3] = (__bf16)(x.w * rx);
    oy[0] = (__bf16)(y.x * ry); oy[1] = (__bf16)(y.y * ry);
    oy[2] = (__bf16)(y.z * ry); oy[3] = (__bf16)(y.w * ry);
    *(bf16x4_t*)(zb + (size_t)w * D + l * 4)           = ox;
    *(bf16x4_t*)(zb + (size_t)(w + NHALF) * D + l * 4) = oy;

    if (l == 0) {
        const float p = sxy * rx * ry;
        g_pos[w]         = p;
        g_pos[w + NHALF] = p;
    }
}

// ---------------- kernel 2: full-matrix sim, row-sums only ----------------
// Symmetric sim: full matrix (2x MFMA vs triangle) but row-sums accumulate purely in
// registers -> per-element epilogue is {mul, exp, add}. No cross-lane shfl reduction,
// no per-strip column atomics, no triangle masking. Grid is perfectly uniform:
// 32 row-blocks x 32 col-chunks = 1024 blocks; each of the 4 waves owns 64 rows x
// 256 cols (16 col-strips), A fragments register-resident for the whole chunk,
// B strips double-buffered in registers. The 4 waves of a block read identical B
// strips -> L1 broadcast; zb (4 MB) is L2-resident.
__global__ __launch_bounds__(256, 2) void sim_kernel(const __bf16* __restrict__ zb,
                                                     float* __restrict__ g_denom) {
    const int tid    = threadIdx.x;
    const int l      = tid & 63;
    const int lane15 = l & 15;
    const int quad   = l >> 4;

    const int rb = blockIdx.x >> 5;            // row block  [0,32)
    const int cb = blockIdx.x & 31;            // col chunk  [0,32)
    const int r0 = rb * 256 + (tid >> 6) * 64; // this wave's 64-row band
    const int c0 = cb * 256;                   // this wave's 256-col chunk

    // A fragments: 64 rows x K=256 held for the whole chunk
    bf16x8_t af[4][8];
    {
        const __bf16* abase = zb + (size_t)(r0 + lane15) * D + quad * 8;
        #pragma unroll
        for (int mi = 0; mi < 4; ++mi)
            #pragma unroll
            for (int kc = 0; kc < 8; ++kc)
                af[mi][kc] = *(const bf16x8_t*)(abase + (size_t)mi * 16 * D + kc * 32);
    }

    float rs[4] = {0.f, 0.f, 0.f, 0.f};

    bf16x8_t b0[8], b1[8];
    auto loadB = [&](int s, bf16x8_t* dst) {
        const __bf16* bbase = zb + (size_t)(c0 + s * 16 + lane15) * D + quad * 8;
        #pragma unroll
        for (int kc = 0; kc < 8; ++kc)
            dst[kc] = *(const bf16x8_t*)(bbase + kc * 32);
    };
    auto compute = [&](int s, const bf16x8_t* bfr) {
        f32x4_t acc[4] = {{0.f,0.f,0.f,0.f},{0.f,0.f,0.f,0.f},{0.f,0.f,0.f,0.f},{0.f,0.f,0.f,0.f}};
        #pragma unroll
        for (int kc = 0; kc < 8; ++kc)
            #pragma unroll
            for (int mi = 0; mi < 4; ++mi)
                acc[mi] = __builtin_amdgcn_mfma_f32_16x16x32_bf16(bfr[kc], af[mi][kc], acc[mi], 0, 0, 0);
        // acc[mi]: S-row = r0+16*mi+lane15 (lane), S-col = cs+quad*4+t (reg)
        const int cs = c0 + s * 16;
        const int dd = cs - r0;                // wave-uniform
        if (dd >= 0 && dd < 64) {
            // this strip contains the wave's diagonal block: zero self-similarity
            #pragma unroll
            for (int mi = 0; mi < 4; ++mi) {
                #pragma unroll
                for (int t = 0; t < 4; ++t) {
                    float e = __expf(2.0f * acc[mi][t]);
                    if (dd == 16 * mi && (quad * 4 + t) == lane15) e = 0.0f;
                    rs[mi] += e;
                }
            }
        } else {
            #pragma unroll
            for (int mi = 0; mi < 4; ++mi)
                #pragma unroll
                for (int t = 0; t < 4; ++t)
                    rs[mi] += __expf(2.0f * acc[mi][t]);
        }
    };

    loadB(0, b0);
    int s = 0;
    while (true) {
        if (s + 1 < 16) loadB(s + 1, b1);
        compute(s, b0);
        if (++s >= 16) break;
        if (s + 1 < 16) loadB(s + 1, b0);
        compute(s, b1);
        if (++s >= 16) break;
    }

    // row sums: 4 lanes (quads) share each row; reduce then one atomic per row
    #pragma unroll
    for (int mi = 0; mi < 4; ++mi) {
        rs[mi] += __shfl_xor(rs[mi], 16, 64);
        rs[mi] += __shfl_xor(rs[mi], 32, 64);
    }
    if (l < 16) {
        #pragma unroll
        for (int mi = 0; mi < 4; ++mi)
            atomicAdd(&g_denom[r0 + 16 * mi + l], rs[mi]);
    }
}

// ---------------- kernel 3: finalize -> scalar loss ----------------
__global__ __launch_bounds__(256) void fin_kernel(const float* __restrict__ g_denom,
                                                  const float* __restrict__ g_pos,
                                                  float* __restrict__ out) {
    const int tid = threadIdx.x;
    float local = 0.0f;
    for (int k = tid; k < N2; k += 256)
        local += logf(g_denom[k]) - 2.0f * g_pos[k];
    #pragma unroll
    for (int off = 32; off; off >>= 1) local += __shfl_xor(local, off, 64);
    __shared__ float sw[4];
    if ((tid & 63) == 0) sw[tid >> 6] = local;
    __syncthreads();
    if (tid == 0) out[0] = (sw[0] + sw[1] + sw[2] + sw[3]) / (float)N2;
}

extern "C" void kernel_launch(void* const* d_in, const int* in_sizes, int n_in,
                              void* d_out, int out_size, void* d_ws, size_t ws_size,
                              hipStream_t stream) {
    const float* emb_i = (const float*)d_in[0];
    const float* emb_j = (const float*)d_in[1];

    __bf16* zb      = (__bf16*)d_ws;                                 // 4 MB
    float*  g_denom = (float*)((char*)d_ws + (size_t)N2 * D * 2);    // 8192 fp32
    float*  g_pos   = g_denom + N2;                                  // 8192 fp32
    float*  out     = (float*)d_out;

    prep_kernel<<<NHALF / 4, 256, 0, stream>>>(emb_i, emb_j, zb, g_pos, g_denom);
    sim_kernel<<<1024, 256, 0, stream>>>(zb, g_denom);   // 4096 uniform waves
    fin_kernel<<<1, 256, 0, stream>>>(g_denom, g_pos, out);
}